// Round 9
// baseline (183.967 us; speedup 1.0000x reference)
//
#include <hip/hip_runtime.h>
#include <math.h>
#include <limits.h>

namespace {

constexpr int LNUM = 2097152;        // L
constexpr int NROW = 5;              // N
constexpr int NSER = 10;             // rows total (0..4 rppg, 5..9 ppg)
constexpr int TPB = 256;
constexpr int CHUNK = 4096;          // elements per block
constexpr int CPR = LNUM / CHUNK;    // 512 chunks per row
constexpr int NBLK = NSER * CPR;     // 5120
constexpr int KIT = 4;               // iterations per wave (256 elems each)
constexpr int SLOT = 172;            // max candidates per 1024-elem region
constexpr int NREG = NBLK * 4;       // 20480 wave regions
constexpr int RPR = NREG / NSER;     // 2048 regions per row

struct Agg { int first; int last; int c; double s; };

__device__ __forceinline__ Agg combine(const Agg& a, const Agg& b) {
  // ordered segment-concat monoid: a LEFT, b RIGHT (non-commutative)
  Agg r;
  r.first = (a.first >= 0) ? a.first : b.first;
  r.last  = (b.last >= 0) ? b.last : a.last;
  r.s = a.s + b.s;
  r.c = a.c + b.c;
  if (a.last >= 0 && b.first >= 0) {
    r.s += (double)(1.0f / (float)(b.first - a.last));
    r.c += 1;
  }
  return r;
}

__device__ __forceinline__ const float* row_ptr(const float* rppg,
                                                const float* ppg, int rw) {
  return (rw < NROW) ? rppg + (size_t)rw * LNUM
                     : ppg + (size_t)(rw - NROW) * LNUM;
}

// (verbatim from R6-proven code)
__device__ __forceinline__ void window4(const float* __restrict__ x, int p0,
                                        float X[4], float w[4]) {
  const float4 f = *reinterpret_cast<const float4*>(x + p0);
  X[0] = f.x; X[1] = f.y; X[2] = f.z; X[3] = f.w;
  float Y[14];
  Y[5] = X[0]; Y[6] = X[1]; Y[7] = X[2]; Y[8] = X[3];
  Y[1] = __shfl_up(X[0], 1);  Y[2] = __shfl_up(X[1], 1);
  Y[3] = __shfl_up(X[2], 1);  Y[4] = __shfl_up(X[3], 1);
  Y[0] = __shfl_up(X[3], 2);
  Y[9] = __shfl_down(X[0], 1);  Y[10] = __shfl_down(X[1], 1);
  Y[11] = __shfl_down(X[2], 1); Y[12] = __shfl_down(X[3], 1);
  Y[13] = __shfl_down(X[0], 2);
  const int lane = threadIdx.x & 63;
  if (lane == 0) {
#pragma unroll
    for (int j = 0; j < 5; ++j) {
      int g = p0 - 5 + j;
      Y[j] = (g >= 0) ? x[g] : -INFINITY;
    }
  } else if (lane == 1) {
    int g = p0 - 5;
    Y[0] = (g >= 0) ? x[g] : -INFINITY;
  }
  if (lane == 63) {
#pragma unroll
    for (int j = 0; j < 5; ++j) {
      int g = p0 + 4 + j;
      Y[9 + j] = (g < LNUM) ? x[g] : -INFINITY;
    }
  } else if (lane == 62) {
    int g = p0 + 8;
    Y[13] = (g < LNUM) ? x[g] : -INFINITY;
  }
  float m2[13];
#pragma unroll
  for (int i = 0; i < 13; ++i) m2[i] = fmaxf(Y[i], Y[i + 1]);
  float m4[11];
#pragma unroll
  for (int i = 0; i < 11; ++i) m4[i] = fmaxf(m2[i], m2[i + 2]);
  float m8[7];
#pragma unroll
  for (int i = 0; i < 7; ++i) m8[i] = fmaxf(m4[i], m4[i + 4]);
#pragma unroll
  for (int t = 0; t < 4; ++t) w[t] = fmaxf(m8[t], m8[t + 3]);  // Y[t..t+10]
}

// Pass 1: per-chunk {sum, peak-value-sum, peak-count} (f64 path UNCHANGED
// from the bit-exact R6 version) + per-wave candidate compaction:
// (pos,val) of every window-max candidate, threshold-independent, written
// via ballot+popcount ranking to region wbase = (bid*4+wid)*SLOT.
__global__ __launch_bounds__(TPB) void stats_kernel(
    const float* __restrict__ rppg, const float* __restrict__ ppg,
    double* __restrict__ psum, double* __restrict__ ppk,
    int* __restrict__ pnpk,
    int* __restrict__ wpos, float* __restrict__ wval,
    int* __restrict__ wcnt) {
  const int bid = blockIdx.x;
  const int rw = bid >> 9;          // /CPR
  const int chunk = bid & (CPR - 1);
  const float* x = row_ptr(rppg, ppg, rw);
  const int lane = threadIdx.x & 63;
  const int wid = threadIdx.x >> 6;
  const int segbase = chunk * CHUNK + wid * 1024;
  const int region = bid * 4 + wid;
  const int wbase = region * SLOT;

  double tsum = 0.0, tpk = 0.0;
  int tn = 0;
  int wcount = 0;  // wave-uniform running candidate count
  for (int k = 0; k < KIT; ++k) {
    const int p0 = segbase + k * 256 + 4 * lane;
    float X[4], w[4];
    window4(x, p0, X, w);
    int off = -1;
    float pv = 0.0f;
#pragma unroll
    for (int t = 0; t < 4; ++t) {
      tsum += (double)X[t];
      if (X[t] == w[t]) { tpk += (double)X[t]; ++tn; off = t; pv = X[t]; }
    }
    const bool cand = (off >= 0);  // <=1 per 4 elems (peaks >=6 apart)
    const unsigned long long bal = __ballot(cand);
    const int rank = __popcll(bal & ((1ull << lane) - 1ull));
    if (cand) {
      wpos[wbase + wcount + rank] = p0 + off;
      wval[wbase + wcount + rank] = pv;
    }
    wcount += __popcll(bal);
  }
  if (lane == 0) wcnt[region] = wcount;

#pragma unroll
  for (int off = 32; off > 0; off >>= 1) {
    tsum += __shfl_down(tsum, off);
    tpk  += __shfl_down(tpk, off);
    tn   += __shfl_down(tn, off);
  }
  __shared__ double wsum[4], wpk[4];
  __shared__ int wn[4];
  if (lane == 0) { wsum[wid] = tsum; wpk[wid] = tpk; wn[wid] = tn; }
  __syncthreads();
  if (threadIdx.x == 0) {
    psum[bid] = wsum[0] + wsum[1] + wsum[2] + wsum[3];
    ppk[bid]  = wpk[0] + wpk[1] + wpk[2] + wpk[3];
    pnpk[bid] = wn[0] + wn[1] + wn[2] + wn[3];
  }
}

// Tiny: per-row raw-domain threshold from chunk partials. (verbatim R6)
// x_norm > mean_pk_norm/2  <=>  x > (mu + mean_pk_raw)/2  (affine, sd cancels)
__global__ __launch_bounds__(TPB) void thresh_kernel(
    const double* __restrict__ psum, const double* __restrict__ ppk,
    const int* __restrict__ pnpk, double* __restrict__ thr) {
  const int r = blockIdx.x;  // 0..9
  const int t = threadIdx.x;
  const int lane = t & 63;
  const int wid = t >> 6;
  double s0 = psum[r * CPR + t] + psum[r * CPR + t + 256];
  double p0 = ppk[r * CPR + t] + ppk[r * CPR + t + 256];
  int n0 = pnpk[r * CPR + t] + pnpk[r * CPR + t + 256];
#pragma unroll
  for (int off = 32; off > 0; off >>= 1) {
    s0 += __shfl_down(s0, off);
    p0 += __shfl_down(p0, off);
    n0 += __shfl_down(n0, off);
  }
  __shared__ double ws[4], wp[4];
  __shared__ int wn[4];
  if (lane == 0) { ws[wid] = s0; wp[wid] = p0; wn[wid] = n0; }
  __syncthreads();
  if (t == 0) {
    double S = ws[0] + ws[1] + ws[2] + ws[3];
    double P = wp[0] + wp[1] + wp[2] + wp[3];
    double Nn = (double)(wn[0] + wn[1] + wn[2] + wn[3]);
    thr[r] = 0.5 * (S / (double)LNUM + P / Nn);
  }
}

// Pass 2: gap scan over COMPACTED candidate lists — no input re-read, no
// re-windowing. One wave per region (<=172 entries -> 3 sub-iters of 64).
// Filter val > thr; prev peak via the R6-proven shfl_up max-scan over
// positions (increasing with index); wave-uniform carry links sub-iters.
// One Agg per region, written directly (no block combine needed).
__global__ __launch_bounds__(TPB) void gapc_kernel(
    const int* __restrict__ wpos, const float* __restrict__ wval,
    const int* __restrict__ wcnt, const double* __restrict__ thr,
    int* __restrict__ afirst, int* __restrict__ alast,
    double* __restrict__ asum, int* __restrict__ acnt) {
  const int lane = threadIdx.x & 63;
  const int wid = threadIdx.x >> 6;
  const int region = blockIdx.x * 4 + wid;
  const int rw = region / RPR;
  const float th = (float)thr[rw];
  const int cnt = wcnt[region];
  const int base = region * SLOT;

  double lsum = 0.0;
  int lcnt = 0;
  int lfirst = INT_MAX;
  int carry = -1;  // wave-uniform
  for (int k = 0; k < 3; ++k) {
    const int i = k * 64 + lane;
    int pk = -1;
    if (i < cnt) {
      float v = wval[base + i];
      if (v > th) pk = wpos[base + i];
    }
    if (pk >= 0 && lfirst == INT_MAX) lfirst = pk;
    int m = pk;
#pragma unroll
    for (int off = 1; off < 64; off <<= 1) {
      int u = __shfl_up(m, off);
      if (lane >= off) m = max(m, u);
    }
    int excl = __shfl_up(m, 1);
    int prev = (lane == 0) ? carry : max(excl, carry);
    if (pk >= 0 && prev >= 0) {
      lsum += (double)(1.0f / (float)(pk - prev));
      ++lcnt;
    }
    int lastall = __shfl(m, 63);
    carry = max(carry, lastall);
  }
#pragma unroll
  for (int off = 32; off > 0; off >>= 1) {
    lsum += __shfl_down(lsum, off);
    lcnt += __shfl_down(lcnt, off);
    lfirst = min(lfirst, __shfl_down(lfirst, off));
  }
  if (lane == 0) {
    afirst[region] = (lfirst == INT_MAX) ? -1 : lfirst;
    alast[region] = carry;
    acnt[region] = lcnt;
    asum[region] = lsum;
  }
}

// Final: one block; per row combine the 2048 region Aggs in order -> hr,
// then the score. Thread t covers regions [8t, 8t+8) sequentially (ordered),
// then the R6-proven ordered shfl tree + cross-wave combine.
__global__ __launch_bounds__(TPB) void final_kernel(
    const int* __restrict__ afirst, const int* __restrict__ alast,
    const double* __restrict__ asum, const int* __restrict__ acnt,
    const int* __restrict__ fsp, float* __restrict__ out) {
  __shared__ Agg waggs[4];
  __shared__ double shr[NSER];
  const int t = threadIdx.x;
  const int lane = t & 63;
  const int wid = t >> 6;
  for (int r = 0; r < NSER; ++r) {
    const int i0 = r * RPR + 8 * t;
    Agg a0; a0.first = afirst[i0]; a0.last = alast[i0];
    a0.c = acnt[i0];               a0.s = asum[i0];
#pragma unroll
    for (int j = 1; j < 8; ++j) {
      Agg aj; aj.first = afirst[i0 + j]; aj.last = alast[i0 + j];
      aj.c = acnt[i0 + j];               aj.s = asum[i0 + j];
      a0 = combine(a0, aj);
    }
#pragma unroll
    for (int off = 1; off < 64; off <<= 1) {
      Agg b;
      b.first = __shfl_down(a0.first, off);
      b.last  = __shfl_down(a0.last, off);
      b.c     = __shfl_down(a0.c, off);
      b.s     = __shfl_down(a0.s, off);
      a0 = combine(a0, b);
    }
    if (lane == 0) waggs[wid] = a0;
    __syncthreads();
    if (t == 0) {
      Agg rr = waggs[0];
      rr = combine(rr, waggs[1]);
      rr = combine(rr, waggs[2]);
      rr = combine(rr, waggs[3]);
      shr[r] = 60.0 * (double)fsp[0] * rr.s / (double)rr.c;
    }
    __syncthreads();
  }
  if (t == 0) {
    double acc = 0.0;
    for (int r = 0; r < NROW; ++r)
      acc += fabs(shr[NROW + r] - shr[r]) / shr[NROW + r];
    out[0] = (float)(acc / (double)NROW);
  }
}

}  // namespace

extern "C" void kernel_launch(void* const* d_in, const int* in_sizes, int n_in,
                              void* d_out, int out_size, void* d_ws, size_t ws_size,
                              hipStream_t stream) {
  const float* rppg = (const float*)d_in[0];
  const float* ppg  = (const float*)d_in[1];
  const int* fsp    = (const int*)d_in[2];
  float* out        = (float*)d_out;
  char* ws          = (char*)d_ws;

  // ws layout (all 8B-aligned; total ~28.8 MB of the provided workspace)
  double* psum   = (double*)(ws);              // 5120*8  = 40960
  double* ppk    = (double*)(ws + 40960);      // 40960
  int*    pnpk   = (int*)(ws + 81920);         // 20480
  double* thr    = (double*)(ws + 102400);     // 80
  int*    afirst = (int*)(ws + 103424);        // 20480*4 = 81920
  int*    alast  = (int*)(ws + 185344);        // 81920
  int*    acnt   = (int*)(ws + 267264);        // 81920
  double* asum   = (double*)(ws + 349184);     // 20480*8 = 163840
  int*    wcnt   = (int*)(ws + 513024);        // 81920
  int*    wpos   = (int*)(ws + 594944);        // 20480*172*4 = 14090240
  float*  wval   = (float*)(ws + 14685184);    // 14090240

  stats_kernel<<<NBLK, TPB, 0, stream>>>(rppg, ppg, psum, ppk, pnpk,
                                         wpos, wval, wcnt);
  thresh_kernel<<<NSER, TPB, 0, stream>>>(psum, ppk, pnpk, thr);
  gapc_kernel<<<NBLK, TPB, 0, stream>>>(wpos, wval, wcnt, thr,
                                        afirst, alast, asum, acnt);
  final_kernel<<<1, TPB, 0, stream>>>(afirst, alast, asum, acnt, fsp, out);
  (void)in_sizes; (void)n_in; (void)out_size; (void)ws_size;
}